// Round 6
// baseline (209.888 us; speedup 1.0000x reference)
//
#include <hip/hip_runtime.h>
#include <hip/hip_bf16.h>

#define FDIM 128
#define BROWS 32     // i1 rows per bucket: bin = i1>>5, loc = i1&31
#define NBLK 128     // partition blocks for hist/scatter (64B single-owner runs)

typedef __attribute__((ext_vector_type(8))) short short8v;
typedef __attribute__((ext_vector_type(4))) float f32x4;
typedef __attribute__((ext_vector_type(2))) _Float16 half2v;

// ---- bf16 helpers (for gemm's 3-term split; manual RNE) ----
static __device__ __forceinline__ unsigned short f2bf(float x) {
    unsigned u = __float_as_uint(x);
    unsigned r = 0x7fffu + ((u >> 16) & 1u);
    return (unsigned short)((u + r) >> 16);
}
static __device__ __forceinline__ float bf2f(unsigned short h) {
    return __uint_as_float((unsigned)h << 16);
}
static __device__ __forceinline__ void split2(float v, short& h, short& l) {
    unsigned short hh = f2bf(v);
    h = (short)hh;
    l = (short)f2bf(v - bf2f(hh));
}

// ---- f16 helpers ----
static __device__ __forceinline__ half2v u2h(unsigned u) {
    union { unsigned u; half2v h; } c; c.u = u; return c.h;
}
static __device__ __forceinline__ unsigned pack2h(float a, float b) {
    union { unsigned u; half2v h; } c;
    c.h[0] = (_Float16)a; c.h[1] = (_Float16)b; return c.u;
}
static __device__ __forceinline__ unsigned short f2h(float x) {
    union { unsigned short s; _Float16 h; } c; c.h = (_Float16)x; return c.s;
}
static __device__ __forceinline__ float fdot2(half2v a, half2v b, float c) {
#if defined(__has_builtin) && __has_builtin(__builtin_amdgcn_fdot2)
    return __builtin_amdgcn_fdot2(a, b, c, false);
#else
    return fmaf((float)a[1], (float)b[1], fmaf((float)a[0], (float)b[0], c));
#endif
}

// ---- k1: G = F @ (W + W^T) via MFMA bf16 3-term split (round-3-proven inline Ws
// staging); epilogue stores G as f16 for the fdot2 edge kernel. ----
__global__ __launch_bounds__(512, 4) void gemm_mfma(
    const float* __restrict__ Fm, const float* __restrict__ W,
    unsigned short* __restrict__ Gh, int N) {
    __shared__ __align__(16) unsigned short sH[128 * 136];
    __shared__ __align__(16) unsigned short sL[128 * 136];

    for (int idx = threadIdx.x; idx < 128 * 128; idx += 512) {
        int i = idx >> 7, j = idx & 127;
        float w = W[idx] + W[j * 128 + i];
        short h, l;
        split2(w, h, l);
        sH[i * 136 + j] = (unsigned short)h;
        sL[i * 136 + j] = (unsigned short)l;
    }
    __syncthreads();

    const int wid  = threadIdx.x >> 6;
    const int lane = threadIdx.x & 63;
    const int ar   = lane & 15;
    const int kg   = lane >> 4;
    const int row0 = blockIdx.x * 128 + wid * 16;
    const int gr   = row0 + ar;
    const bool rv  = gr < N;
    const float* fp = Fm + (size_t)gr * FDIM;

    f32x4 acc[8];
#pragma unroll
    for (int t = 0; t < 8; ++t) acc[t] = (f32x4){0.f, 0.f, 0.f, 0.f};

#pragma unroll
    for (int ks = 0; ks < 4; ++ks) {
        const int k0 = ks * 32 + kg * 8;
        float4 fa = make_float4(0.f, 0.f, 0.f, 0.f);
        float4 fb = make_float4(0.f, 0.f, 0.f, 0.f);
        if (rv) {
            fa = *(const float4*)(fp + k0);
            fb = *(const float4*)(fp + k0 + 4);
        }
        short8v ah, al;
        {
            short h, l;
            split2(fa.x, h, l); ah[0] = h; al[0] = l;
            split2(fa.y, h, l); ah[1] = h; al[1] = l;
            split2(fa.z, h, l); ah[2] = h; al[2] = l;
            split2(fa.w, h, l); ah[3] = h; al[3] = l;
            split2(fb.x, h, l); ah[4] = h; al[4] = l;
            split2(fb.y, h, l); ah[5] = h; al[5] = l;
            split2(fb.z, h, l); ah[6] = h; al[6] = l;
            split2(fb.w, h, l); ah[7] = h; al[7] = l;
        }
#pragma unroll
        for (int ct = 0; ct < 8; ++ct) {
            const short8v bh = *(const short8v*)(sH + (ct * 16 + ar) * 136 + k0);
            const short8v bl = *(const short8v*)(sL + (ct * 16 + ar) * 136 + k0);
            acc[ct] = __builtin_amdgcn_mfma_f32_16x16x32_bf16(ah, bh, acc[ct], 0, 0, 0);
            acc[ct] = __builtin_amdgcn_mfma_f32_16x16x32_bf16(ah, bl, acc[ct], 0, 0, 0);
            acc[ct] = __builtin_amdgcn_mfma_f32_16x16x32_bf16(al, bh, acc[ct], 0, 0, 0);
        }
    }

#pragma unroll
    for (int r = 0; r < 4; ++r) {
        const int orow = row0 + kg * 4 + r;
        if (orow < N) {
#pragma unroll
            for (int ct = 0; ct < 8; ++ct)
                Gh[(size_t)orow * FDIM + ct * 16 + ar] = f2h(acc[ct][r]);
        }
    }
}

// ---- k2: LDS histogram per partition block -> M[k][b]; block 0 zeroes out[] ----
__global__ __launch_bounds__(1024) void k_hist(const int* __restrict__ idx, int E,
                                               int nb, unsigned* __restrict__ M,
                                               float* __restrict__ out, int Mout) {
    if (blockIdx.x == 0) {
        for (int i = threadIdx.x; i < Mout; i += 1024) out[i] = 0.f;
    }
    extern __shared__ unsigned cnt[];
    for (int i = threadIdx.x; i < nb; i += 1024) cnt[i] = 0;
    __syncthreads();
    int chunk = (E + NBLK - 1) / NBLK;
    int s = blockIdx.x * chunk;
    int e_end = min(E, s + chunk);
    for (int e = s + threadIdx.x; e < e_end; e += 1024) {
        int i1 = idx[E + e];
        atomicAdd(&cnt[i1 >> 5], 1u);
    }
    __syncthreads();
    for (int i = threadIdx.x; i < nb; i += 1024)
        M[(size_t)blockIdx.x * nb + i] = cnt[i];
}

// ---- k3a: wave-per-bucket exclusive scan over k of M[k][b]; emits tot[b] ----
__global__ __launch_bounds__(256) void k_mscan2(unsigned* __restrict__ M, int nb,
                                                unsigned* __restrict__ tot) {
    int b = blockIdx.x * 4 + (threadIdx.x >> 6);
    int lane = threadIdx.x & 63;
    if (b >= nb) return;
    unsigned m0 = M[(size_t)(2 * lane + 0) * nb + b];
    unsigned m1 = M[(size_t)(2 * lane + 1) * nb + b];
    unsigned s = m0 + m1;
    unsigned incl = s;
#pragma unroll
    for (int d = 1; d < 64; d <<= 1) {
        unsigned u = __shfl_up(incl, d, 64);
        if (lane >= d) incl += u;
    }
    unsigned run = incl - s;
    M[(size_t)(2 * lane + 0) * nb + b] = run; run += m0;
    M[(size_t)(2 * lane + 1) * nb + b] = run;
    if (lane == 63) tot[b] = incl;
}

// ---- k3b: single-block exclusive scan of tot -> bucketStart ----
__global__ __launch_bounds__(256) void k_bscan(const unsigned* __restrict__ tot, int nb,
                                               unsigned* __restrict__ bucketStart) {
    __shared__ unsigned wS[4];
    int t = threadIdx.x;
    unsigned v0, v1, v2, v3, v4, v5, v6, v7;
    int b0 = t * 8;
    v0 = (b0 + 0 < nb) ? tot[b0 + 0] : 0u;
    v1 = (b0 + 1 < nb) ? tot[b0 + 1] : 0u;
    v2 = (b0 + 2 < nb) ? tot[b0 + 2] : 0u;
    v3 = (b0 + 3 < nb) ? tot[b0 + 3] : 0u;
    v4 = (b0 + 4 < nb) ? tot[b0 + 4] : 0u;
    v5 = (b0 + 5 < nb) ? tot[b0 + 5] : 0u;
    v6 = (b0 + 6 < nb) ? tot[b0 + 6] : 0u;
    v7 = (b0 + 7 < nb) ? tot[b0 + 7] : 0u;
    unsigned l0 = 0, l1 = v0, l2 = l1 + v1, l3 = l2 + v2, l4 = l3 + v3,
             l5 = l4 + v4, l6 = l5 + v5, l7 = l6 + v6;
    unsigned s = l7 + v7;
    int lane = t & 63, wid = t >> 6;
    unsigned incl = s;
    for (int d = 1; d < 64; d <<= 1) {
        unsigned u = __shfl_up(incl, d, 64);
        if (lane >= d) incl += u;
    }
    if (lane == 63) wS[wid] = incl;
    __syncthreads();
    unsigned wOff = 0;
    for (int i = 0; i < wid; ++i) wOff += wS[i];
    unsigned base = wOff + incl - s;
    if (b0 + 0 < nb) bucketStart[b0 + 0] = base + l0;
    if (b0 + 1 < nb) bucketStart[b0 + 1] = base + l1;
    if (b0 + 2 < nb) bucketStart[b0 + 2] = base + l2;
    if (b0 + 3 < nb) bucketStart[b0 + 3] = base + l3;
    if (b0 + 4 < nb) bucketStart[b0 + 4] = base + l4;
    if (b0 + 5 < nb) bucketStart[b0 + 5] = base + l5;
    if (b0 + 6 < nb) bucketStart[b0 + 6] = base + l6;
    if (b0 + 7 < nb) bucketStart[b0 + 7] = base + l7;
    if (t == 255) bucketStart[nb] = base + s;
}

// ---- k4: scatter via LDS cursors (u32 pack: i0 | m<<16 | loc<<26).
// NBLK=128 + 1024thr: each (block,bucket) run ~12 edges x 4B -> minimal XCD bounce ----
__global__ __launch_bounds__(1024) void k_scatter(const int* __restrict__ idx,
                                                  const int* __restrict__ mol, int E,
                                                  int nb, const unsigned* __restrict__ M,
                                                  const unsigned* __restrict__ bucketStart,
                                                  unsigned* __restrict__ sortedE) {
    extern __shared__ unsigned cur[];
    for (int i = threadIdx.x; i < nb; i += 1024)
        cur[i] = M[(size_t)blockIdx.x * nb + i] + bucketStart[i];
    __syncthreads();
    int chunk = (E + NBLK - 1) / NBLK;
    int s = blockIdx.x * chunk;
    int e_end = min(E, s + chunk);
    for (int e = s + threadIdx.x; e < e_end; e += 1024) {
        int i0 = idx[e];
        int i1 = idx[E + e];
        int m  = mol[e];
        int b  = i1 >> 5;
        int loc = i1 & 31;
        unsigned pos = atomicAdd(&cur[b], 1u);
        sortedE[pos] = (unsigned)i0 | ((unsigned)m << 16) | ((unsigned)loc << 26);
    }
}

// ---- k5: edge kernel — round-2 bucketed structure + f16 fdot2 dot + 4 chains.
// One block per bucket: F window (32 rows) staged f16 in LDS; per iter each wave
// handles 16 edges (4 chains x 4 sub-edges x 16 feature-lanes); v_dot2_f32_f16
// does unpack+2 MACs per instruction (exact f16 products, f32 accumulate). ----
__global__ __launch_bounds__(512, 6) void edge_kernel(
    const unsigned short* __restrict__ Gh, const float* __restrict__ Fm,
    const unsigned* __restrict__ sortedE, const unsigned* __restrict__ bucketStart,
    float* __restrict__ out, int N, int Mout) {
    __shared__ __align__(16) unsigned short sFrow[BROWS * FDIM];   // 8 KB f16
    __shared__ float smol[1024];                                   // 4 KB

    const int b = blockIdx.x;
    const int row0 = b * BROWS;
    const int nrow = min(BROWS, N - row0);

    for (int k = threadIdx.x; k < nrow * 16; k += 512) {
        int r = k >> 4, g = k & 15;               // 16B granule = 8 f16
        const float4* src = (const float4*)(Fm + (size_t)(row0 + r) * FDIM + g * 8);
        float4 v0 = src[0], v1 = src[1];
        uint4 u;
        u.x = pack2h(v0.x, v0.y);
        u.y = pack2h(v0.z, v0.w);
        u.z = pack2h(v1.x, v1.y);
        u.w = pack2h(v1.z, v1.w);
        *(uint4*)(sFrow + r * FDIM + g * 8) = u;
    }
    for (int i = threadIdx.x; i < 1024; i += 512) smol[i] = 0.f;
    __syncthreads();

    const int s = (int)bucketStart[b];
    const int e_end = (int)bucketStart[b + 1];
    const int lane = threadIdx.x & 63;
    const int sub  = lane >> 4;      // 0..3: edge within quad
    const int t16  = lane & 15;      // feature slice
    const int off16 = t16 * 8;
    const int wid  = threadIdx.x >> 6;

#define DOT8(p, g, f) \
    p = fdot2(u2h((g).x), u2h((f).x), p); \
    p = fdot2(u2h((g).y), u2h((f).y), p); \
    p = fdot2(u2h((g).z), u2h((f).z), p); \
    p = fdot2(u2h((g).w), u2h((f).w), p);

    int base = s + wid * 16;
    unsigned pk0 = 0u, pk1 = 0u, pk2 = 0u, pk3 = 0u;
    if (base + sub < e_end)      pk0 = sortedE[base + sub];
    if (base + 4 + sub < e_end)  pk1 = sortedE[base + 4 + sub];
    if (base + 8 + sub < e_end)  pk2 = sortedE[base + 8 + sub];
    if (base + 12 + sub < e_end) pk3 = sortedE[base + 12 + sub];

    while (base < e_end) {
        const int nbase = base + 128;             // 8 waves x 16 edges
        unsigned npk0 = 0u, npk1 = 0u, npk2 = 0u, npk3 = 0u;
        if (nbase + sub < e_end)      npk0 = sortedE[nbase + sub];
        if (nbase + 4 + sub < e_end)  npk1 = sortedE[nbase + 4 + sub];
        if (nbase + 8 + sub < e_end)  npk2 = sortedE[nbase + 8 + sub];
        if (nbase + 12 + sub < e_end) npk3 = sortedE[nbase + 12 + sub];

        const uint4 g0 = *(const uint4*)(Gh + (size_t)(pk0 & 0xffffu) * FDIM + off16);
        const uint4 g1 = *(const uint4*)(Gh + (size_t)(pk1 & 0xffffu) * FDIM + off16);
        const uint4 g2 = *(const uint4*)(Gh + (size_t)(pk2 & 0xffffu) * FDIM + off16);
        const uint4 g3 = *(const uint4*)(Gh + (size_t)(pk3 & 0xffffu) * FDIM + off16);
        const uint4 f0 = *(const uint4*)(sFrow + (pk0 >> 26) * FDIM + off16);
        const uint4 f1 = *(const uint4*)(sFrow + (pk1 >> 26) * FDIM + off16);
        const uint4 f2 = *(const uint4*)(sFrow + (pk2 >> 26) * FDIM + off16);
        const uint4 f3 = *(const uint4*)(sFrow + (pk3 >> 26) * FDIM + off16);

        float p0 = 0.f, p1 = 0.f, p2 = 0.f, p3 = 0.f;
        DOT8(p0, g0, f0);
        DOT8(p1, g1, f1);
        DOT8(p2, g2, f2);
        DOT8(p3, g3, f3);

        p0 += __shfl_xor(p0, 1, 16);
        p1 += __shfl_xor(p1, 1, 16);
        p2 += __shfl_xor(p2, 1, 16);
        p3 += __shfl_xor(p3, 1, 16);
        p0 += __shfl_xor(p0, 2, 16);
        p1 += __shfl_xor(p1, 2, 16);
        p2 += __shfl_xor(p2, 2, 16);
        p3 += __shfl_xor(p3, 2, 16);
        p0 += __shfl_xor(p0, 4, 16);
        p1 += __shfl_xor(p1, 4, 16);
        p2 += __shfl_xor(p2, 4, 16);
        p3 += __shfl_xor(p3, 4, 16);
        p0 += __shfl_xor(p0, 8, 16);
        p1 += __shfl_xor(p1, 8, 16);
        p2 += __shfl_xor(p2, 8, 16);
        p3 += __shfl_xor(p3, 8, 16);

        if (t16 == 0) {
            if (base + sub < e_end)      atomicAdd(&smol[(pk0 >> 16) & 0x3ff], p0);
            if (base + 4 + sub < e_end)  atomicAdd(&smol[(pk1 >> 16) & 0x3ff], p1);
            if (base + 8 + sub < e_end)  atomicAdd(&smol[(pk2 >> 16) & 0x3ff], p2);
            if (base + 12 + sub < e_end) atomicAdd(&smol[(pk3 >> 16) & 0x3ff], p3);
        }
        pk0 = npk0; pk1 = npk1; pk2 = npk2; pk3 = npk3;
        base = nbase;
    }
#undef DOT8
    __syncthreads();

    for (int i = threadIdx.x; i < Mout; i += 512) {
        float v = smol[i];
        if (v != 0.f) atomicAdd(&out[i], v);
    }
}

extern "C" void kernel_launch(void* const* d_in, const int* in_sizes, int n_in,
                              void* d_out, int out_size, void* d_ws, size_t ws_size,
                              hipStream_t stream) {
    const float* Fm = (const float*)d_in[0];
    const float* W  = (const float*)d_in[1];
    const int* idx  = (const int*)d_in[2];
    const int* mol  = (const int*)d_in[3];
    float* out = (float*)d_out;

    const int N = in_sizes[0] / FDIM;   // 50000
    const int E = in_sizes[3];          // 1600000

    const int nb = (N + BROWS - 1) / BROWS;   // 1563 buckets

    // workspace layout (~20 MB)
    char* ws = (char*)d_ws;
    size_t o = 0;
    unsigned short* Gh = (unsigned short*)(ws + o);  o += ((size_t)N * FDIM * 2 + 255) & ~(size_t)255;
    unsigned* sortedE = (unsigned*)(ws + o);         o += ((size_t)E * 4 + 255) & ~(size_t)255;
    unsigned* M = (unsigned*)(ws + o);               o += ((size_t)NBLK * nb * 4 + 255) & ~(size_t)255;
    unsigned* tot = (unsigned*)(ws + o);             o += ((size_t)nb * 4 + 255) & ~(size_t)255;
    unsigned* bucketStart = (unsigned*)(ws + o);     o += ((size_t)(nb + 1) * 4 + 255) & ~(size_t)255;

    gemm_mfma<<<(N + 127) / 128, 512, 0, stream>>>(Fm, W, Gh, N);

    size_t smem = (size_t)nb * 4;
    k_hist<<<NBLK, 1024, smem, stream>>>(idx, E, nb, M, out, out_size);
    k_mscan2<<<(nb + 3) / 4, 256, 0, stream>>>(M, nb, tot);
    k_bscan<<<1, 256, 0, stream>>>(tot, nb, bucketStart);
    k_scatter<<<NBLK, 1024, smem, stream>>>(idx, mol, E, nb, M, bucketStart, sortedE);

    edge_kernel<<<nb, 512, 0, stream>>>(Gh, Fm, sortedE, bucketStart, out, N, out_size);
}

// Round 8
// 189.046 us; speedup vs baseline: 1.1103x; 1.1103x over previous
//
#include <hip/hip_runtime.h>
#include <hip/hip_bf16.h>

#define FDIM 128
#define BROWS 32     // i1 rows per bucket: bin = i1>>5, loc = i1&31
#define NBLK 128     // partition blocks for hist/scatter (64B single-owner runs)
#define NSLICE 32    // reduction slices

typedef __attribute__((ext_vector_type(8))) short short8v;
typedef __attribute__((ext_vector_type(4))) float f32x4;
typedef __attribute__((ext_vector_type(2))) _Float16 half2v;

// ---- bf16 helpers (for gemm's 3-term split; manual RNE) ----
static __device__ __forceinline__ unsigned short f2bf(float x) {
    unsigned u = __float_as_uint(x);
    unsigned r = 0x7fffu + ((u >> 16) & 1u);
    return (unsigned short)((u + r) >> 16);
}
static __device__ __forceinline__ float bf2f(unsigned short h) {
    return __uint_as_float((unsigned)h << 16);
}
static __device__ __forceinline__ void split2(float v, short& h, short& l) {
    unsigned short hh = f2bf(v);
    h = (short)hh;
    l = (short)f2bf(v - bf2f(hh));
}

// ---- f16 helpers ----
static __device__ __forceinline__ half2v u2h(unsigned u) {
    union { unsigned u; half2v h; } c; c.u = u; return c.h;
}
static __device__ __forceinline__ unsigned pack2h(float a, float b) {
    union { unsigned u; half2v h; } c;
    c.h[0] = (_Float16)a; c.h[1] = (_Float16)b; return c.u;
}
static __device__ __forceinline__ unsigned short f2h(float x) {
    union { unsigned short s; _Float16 h; } c; c.h = (_Float16)x; return c.s;
}
static __device__ __forceinline__ float fdot2(half2v a, half2v b, float c) {
#if defined(__has_builtin) && __has_builtin(__builtin_amdgcn_fdot2)
    return __builtin_amdgcn_fdot2(a, b, c, false);
#else
    return fmaf((float)a[1], (float)b[1], fmaf((float)a[0], (float)b[0], c));
#endif
}

// ---- k0: Ws = W + W^T pre-split bf16 hi/lo, ONCE (r5-proven: inlining the
// transposed read into every gemm block cost +13us of uncoalesced L2 traffic) ----
__global__ void make_ws2(const float* __restrict__ W,
                         unsigned short* __restrict__ WsH,
                         unsigned short* __restrict__ WsL) {
    int idx = blockIdx.x * 256 + threadIdx.x;
    int i = idx >> 7, j = idx & 127;
    float w = W[idx] + W[j * 128 + i];
    short h, l;
    split2(w, h, l);
    WsH[idx] = (unsigned short)h;
    WsL[idx] = (unsigned short)l;
}

// ---- k1: G = F @ (W + W^T) via MFMA bf16 3-term split; stores G as f16 ----
__global__ __launch_bounds__(512, 4) void gemm_mfma(
    const float* __restrict__ Fm,
    const unsigned short* __restrict__ WsH, const unsigned short* __restrict__ WsL,
    unsigned short* __restrict__ Gh, int N) {
    __shared__ __align__(16) unsigned short sH[128 * 136];   // stride 272B
    __shared__ __align__(16) unsigned short sL[128 * 136];

    for (int k = threadIdx.x; k < 128 * 16; k += 512) {      // coalesced 16B granules
        int i = k >> 4, g = k & 15;
        *(uint4*)((char*)sH + i * 272 + g * 16) =
            *(const uint4*)((const char*)WsH + i * 256 + g * 16);
        *(uint4*)((char*)sL + i * 272 + g * 16) =
            *(const uint4*)((const char*)WsL + i * 256 + g * 16);
    }
    __syncthreads();

    const int wid  = threadIdx.x >> 6;
    const int lane = threadIdx.x & 63;
    const int ar   = lane & 15;
    const int kg   = lane >> 4;
    const int row0 = blockIdx.x * 128 + wid * 16;
    const int gr   = row0 + ar;
    const bool rv  = gr < N;
    const float* fp = Fm + (size_t)gr * FDIM;

    f32x4 acc[8];
#pragma unroll
    for (int t = 0; t < 8; ++t) acc[t] = (f32x4){0.f, 0.f, 0.f, 0.f};

#pragma unroll
    for (int ks = 0; ks < 4; ++ks) {
        const int k0 = ks * 32 + kg * 8;
        float4 fa = make_float4(0.f, 0.f, 0.f, 0.f);
        float4 fb = make_float4(0.f, 0.f, 0.f, 0.f);
        if (rv) {
            fa = *(const float4*)(fp + k0);
            fb = *(const float4*)(fp + k0 + 4);
        }
        short8v ah, al;
        {
            short h, l;
            split2(fa.x, h, l); ah[0] = h; al[0] = l;
            split2(fa.y, h, l); ah[1] = h; al[1] = l;
            split2(fa.z, h, l); ah[2] = h; al[2] = l;
            split2(fa.w, h, l); ah[3] = h; al[3] = l;
            split2(fb.x, h, l); ah[4] = h; al[4] = l;
            split2(fb.y, h, l); ah[5] = h; al[5] = l;
            split2(fb.z, h, l); ah[6] = h; al[6] = l;
            split2(fb.w, h, l); ah[7] = h; al[7] = l;
        }
#pragma unroll
        for (int ct = 0; ct < 8; ++ct) {
            const short8v bh = *(const short8v*)(sH + (ct * 16 + ar) * 136 + k0);
            const short8v bl = *(const short8v*)(sL + (ct * 16 + ar) * 136 + k0);
            acc[ct] = __builtin_amdgcn_mfma_f32_16x16x32_bf16(ah, bh, acc[ct], 0, 0, 0);
            acc[ct] = __builtin_amdgcn_mfma_f32_16x16x32_bf16(ah, bl, acc[ct], 0, 0, 0);
            acc[ct] = __builtin_amdgcn_mfma_f32_16x16x32_bf16(al, bh, acc[ct], 0, 0, 0);
        }
    }

#pragma unroll
    for (int r = 0; r < 4; ++r) {
        const int orow = row0 + kg * 4 + r;
        if (orow < N) {
#pragma unroll
            for (int ct = 0; ct < 8; ++ct)
                Gh[(size_t)orow * FDIM + ct * 16 + ar] = f2h(acc[ct][r]);
        }
    }
}

// ---- k2: LDS histogram per partition block -> M[k][b] ----
__global__ __launch_bounds__(1024) void k_hist(const int* __restrict__ idx, int E,
                                               int nb, unsigned* __restrict__ M) {
    extern __shared__ unsigned cnt[];
    for (int i = threadIdx.x; i < nb; i += 1024) cnt[i] = 0;
    __syncthreads();
    int chunk = (E + NBLK - 1) / NBLK;
    int s = blockIdx.x * chunk;
    int e_end = min(E, s + chunk);
    for (int e = s + threadIdx.x; e < e_end; e += 1024) {
        int i1 = idx[E + e];
        atomicAdd(&cnt[i1 >> 5], 1u);
    }
    __syncthreads();
    for (int i = threadIdx.x; i < nb; i += 1024)
        M[(size_t)blockIdx.x * nb + i] = cnt[i];
}

// ---- k3a: wave-per-bucket exclusive scan over k of M[k][b]; emits tot[b] ----
__global__ __launch_bounds__(256) void k_mscan2(unsigned* __restrict__ M, int nb,
                                                unsigned* __restrict__ tot) {
    int b = blockIdx.x * 4 + (threadIdx.x >> 6);
    int lane = threadIdx.x & 63;
    if (b >= nb) return;
    unsigned m0 = M[(size_t)(2 * lane + 0) * nb + b];
    unsigned m1 = M[(size_t)(2 * lane + 1) * nb + b];
    unsigned s = m0 + m1;
    unsigned incl = s;
#pragma unroll
    for (int d = 1; d < 64; d <<= 1) {
        unsigned u = __shfl_up(incl, d, 64);
        if (lane >= d) incl += u;
    }
    unsigned run = incl - s;
    M[(size_t)(2 * lane + 0) * nb + b] = run; run += m0;
    M[(size_t)(2 * lane + 1) * nb + b] = run;
    if (lane == 63) tot[b] = incl;
}

// ---- k3b: single-block exclusive scan of tot -> bucketStart ----
__global__ __launch_bounds__(256) void k_bscan(const unsigned* __restrict__ tot, int nb,
                                               unsigned* __restrict__ bucketStart) {
    __shared__ unsigned wS[4];
    int t = threadIdx.x;
    unsigned v0, v1, v2, v3, v4, v5, v6, v7;
    int b0 = t * 8;
    v0 = (b0 + 0 < nb) ? tot[b0 + 0] : 0u;
    v1 = (b0 + 1 < nb) ? tot[b0 + 1] : 0u;
    v2 = (b0 + 2 < nb) ? tot[b0 + 2] : 0u;
    v3 = (b0 + 3 < nb) ? tot[b0 + 3] : 0u;
    v4 = (b0 + 4 < nb) ? tot[b0 + 4] : 0u;
    v5 = (b0 + 5 < nb) ? tot[b0 + 5] : 0u;
    v6 = (b0 + 6 < nb) ? tot[b0 + 6] : 0u;
    v7 = (b0 + 7 < nb) ? tot[b0 + 7] : 0u;
    unsigned l0 = 0, l1 = v0, l2 = l1 + v1, l3 = l2 + v2, l4 = l3 + v3,
             l5 = l4 + v4, l6 = l5 + v5, l7 = l6 + v6;
    unsigned s = l7 + v7;
    int lane = t & 63, wid = t >> 6;
    unsigned incl = s;
    for (int d = 1; d < 64; d <<= 1) {
        unsigned u = __shfl_up(incl, d, 64);
        if (lane >= d) incl += u;
    }
    if (lane == 63) wS[wid] = incl;
    __syncthreads();
    unsigned wOff = 0;
    for (int i = 0; i < wid; ++i) wOff += wS[i];
    unsigned base = wOff + incl - s;
    if (b0 + 0 < nb) bucketStart[b0 + 0] = base + l0;
    if (b0 + 1 < nb) bucketStart[b0 + 1] = base + l1;
    if (b0 + 2 < nb) bucketStart[b0 + 2] = base + l2;
    if (b0 + 3 < nb) bucketStart[b0 + 3] = base + l3;
    if (b0 + 4 < nb) bucketStart[b0 + 4] = base + l4;
    if (b0 + 5 < nb) bucketStart[b0 + 5] = base + l5;
    if (b0 + 6 < nb) bucketStart[b0 + 6] = base + l6;
    if (b0 + 7 < nb) bucketStart[b0 + 7] = base + l7;
    if (t == 255) bucketStart[nb] = base + s;
}

// ---- k4: scatter via LDS cursors (u32 pack: i0 | m<<16 | loc<<26) ----
__global__ __launch_bounds__(1024) void k_scatter(const int* __restrict__ idx,
                                                  const int* __restrict__ mol, int E,
                                                  int nb, const unsigned* __restrict__ M,
                                                  const unsigned* __restrict__ bucketStart,
                                                  unsigned* __restrict__ sortedE) {
    extern __shared__ unsigned cur[];
    for (int i = threadIdx.x; i < nb; i += 1024)
        cur[i] = M[(size_t)blockIdx.x * nb + i] + bucketStart[i];
    __syncthreads();
    int chunk = (E + NBLK - 1) / NBLK;
    int s = blockIdx.x * chunk;
    int e_end = min(E, s + chunk);
    for (int e = s + threadIdx.x; e < e_end; e += 1024) {
        int i0 = idx[e];
        int i1 = idx[E + e];
        int m  = mol[e];
        int b  = i1 >> 5;
        int loc = i1 & 31;
        unsigned pos = atomicAdd(&cur[b], 1u);
        sortedE[pos] = (unsigned)i0 | ((unsigned)m << 16) | ((unsigned)loc << 26);
    }
}

// ---- k5: edge kernel — bucketed f16/fdot2 (r6 loop) + PART-STORE epilogue
// (r2-proven: the global-atomic flush was a ~15us XCD line-bouncing tail) ----
__global__ __launch_bounds__(512, 6) void edge_kernel(
    const unsigned short* __restrict__ Gh, const float* __restrict__ Fm,
    const unsigned* __restrict__ sortedE, const unsigned* __restrict__ bucketStart,
    float* __restrict__ part, int N, int Mout) {
    __shared__ __align__(16) unsigned short sFrow[BROWS * FDIM];   // 8 KB f16
    __shared__ float smol[1024];                                   // 4 KB

    const int b = blockIdx.x;
    const int row0 = b * BROWS;
    const int nrow = min(BROWS, N - row0);

    for (int k = threadIdx.x; k < nrow * 16; k += 512) {
        int r = k >> 4, g = k & 15;               // 16B granule = 8 f16
        const float4* src = (const float4*)(Fm + (size_t)(row0 + r) * FDIM + g * 8);
        float4 v0 = src[0], v1 = src[1];
        uint4 u;
        u.x = pack2h(v0.x, v0.y);
        u.y = pack2h(v0.z, v0.w);
        u.z = pack2h(v1.x, v1.y);
        u.w = pack2h(v1.z, v1.w);
        *(uint4*)(sFrow + r * FDIM + g * 8) = u;
    }
    for (int i = threadIdx.x; i < 1024; i += 512) smol[i] = 0.f;
    __syncthreads();

    const int s = (int)bucketStart[b];
    const int e_end = (int)bucketStart[b + 1];
    const int lane = threadIdx.x & 63;
    const int sub  = lane >> 4;      // 0..3: edge within quad
    const int t16  = lane & 15;      // feature slice
    const int off16 = t16 * 8;
    const int wid  = threadIdx.x >> 6;

#define DOT8(p, g, f) \
    p = fdot2(u2h((g).x), u2h((f).x), p); \
    p = fdot2(u2h((g).y), u2h((f).y), p); \
    p = fdot2(u2h((g).z), u2h((f).z), p); \
    p = fdot2(u2h((g).w), u2h((f).w), p);

    int base = s + wid * 16;
    unsigned pk0 = 0u, pk1 = 0u, pk2 = 0u, pk3 = 0u;
    if (base + sub < e_end)      pk0 = sortedE[base + sub];
    if (base + 4 + sub < e_end)  pk1 = sortedE[base + 4 + sub];
    if (base + 8 + sub < e_end)  pk2 = sortedE[base + 8 + sub];
    if (base + 12 + sub < e_end) pk3 = sortedE[base + 12 + sub];

    while (base < e_end) {
        const int nbase = base + 128;             // 8 waves x 16 edges
        unsigned npk0 = 0u, npk1 = 0u, npk2 = 0u, npk3 = 0u;
        if (nbase + sub < e_end)      npk0 = sortedE[nbase + sub];
        if (nbase + 4 + sub < e_end)  npk1 = sortedE[nbase + 4 + sub];
        if (nbase + 8 + sub < e_end)  npk2 = sortedE[nbase + 8 + sub];
        if (nbase + 12 + sub < e_end) npk3 = sortedE[nbase + 12 + sub];

        const uint4 g0 = *(const uint4*)(Gh + (size_t)(pk0 & 0xffffu) * FDIM + off16);
        const uint4 g1 = *(const uint4*)(Gh + (size_t)(pk1 & 0xffffu) * FDIM + off16);
        const uint4 g2 = *(const uint4*)(Gh + (size_t)(pk2 & 0xffffu) * FDIM + off16);
        const uint4 g3 = *(const uint4*)(Gh + (size_t)(pk3 & 0xffffu) * FDIM + off16);
        const uint4 f0 = *(const uint4*)(sFrow + (pk0 >> 26) * FDIM + off16);
        const uint4 f1 = *(const uint4*)(sFrow + (pk1 >> 26) * FDIM + off16);
        const uint4 f2 = *(const uint4*)(sFrow + (pk2 >> 26) * FDIM + off16);
        const uint4 f3 = *(const uint4*)(sFrow + (pk3 >> 26) * FDIM + off16);

        float p0 = 0.f, p1 = 0.f, p2 = 0.f, p3 = 0.f;
        DOT8(p0, g0, f0);
        DOT8(p1, g1, f1);
        DOT8(p2, g2, f2);
        DOT8(p3, g3, f3);

        p0 += __shfl_xor(p0, 1, 16);
        p1 += __shfl_xor(p1, 1, 16);
        p2 += __shfl_xor(p2, 1, 16);
        p3 += __shfl_xor(p3, 1, 16);
        p0 += __shfl_xor(p0, 2, 16);
        p1 += __shfl_xor(p1, 2, 16);
        p2 += __shfl_xor(p2, 2, 16);
        p3 += __shfl_xor(p3, 2, 16);
        p0 += __shfl_xor(p0, 4, 16);
        p1 += __shfl_xor(p1, 4, 16);
        p2 += __shfl_xor(p2, 4, 16);
        p3 += __shfl_xor(p3, 4, 16);
        p0 += __shfl_xor(p0, 8, 16);
        p1 += __shfl_xor(p1, 8, 16);
        p2 += __shfl_xor(p2, 8, 16);
        p3 += __shfl_xor(p3, 8, 16);

        if (t16 == 0) {
            if (base + sub < e_end)      atomicAdd(&smol[(pk0 >> 16) & 0x3ff], p0);
            if (base + 4 + sub < e_end)  atomicAdd(&smol[(pk1 >> 16) & 0x3ff], p1);
            if (base + 8 + sub < e_end)  atomicAdd(&smol[(pk2 >> 16) & 0x3ff], p2);
            if (base + 12 + sub < e_end) atomicAdd(&smol[(pk3 >> 16) & 0x3ff], p3);
        }
        pk0 = npk0; pk1 = npk1; pk2 = npk2; pk3 = npk3;
        base = nbase;
    }
#undef DOT8
    __syncthreads();

    // plain coalesced stores — no cross-XCD atomic tail
    float* prow = part + (size_t)b * 1024;
    for (int i = threadIdx.x; i < Mout; i += 512) prow[i] = smol[i];
}

// ---- k6a: partial reduce over buckets (NSLICE slices) ----
__global__ __launch_bounds__(256) void k_red1(const float* __restrict__ part, int nb,
                                              float* __restrict__ partial, int Mout) {
    int gid = blockIdx.x * 256 + threadIdx.x;
    int m = gid & 1023;
    int sl = gid >> 10;
    int per = (nb + NSLICE - 1) / NSLICE;
    int b0 = sl * per;
    int b1 = min(nb, b0 + per);
    float s = 0.f;
    if (m < Mout) {
        for (int b = b0; b < b1; ++b) s += part[(size_t)b * 1024 + m];
    }
    partial[sl * 1024 + m] = s;
}

// ---- k6b: final reduce ----
__global__ __launch_bounds__(256) void k_red2(const float* __restrict__ partial,
                                              float* __restrict__ out, int Mout) {
    int m = blockIdx.x * 256 + threadIdx.x;
    if (m < Mout) {
        float s = 0.f;
        for (int sl = 0; sl < NSLICE; ++sl) s += partial[sl * 1024 + m];
        out[m] = s;
    }
}

extern "C" void kernel_launch(void* const* d_in, const int* in_sizes, int n_in,
                              void* d_out, int out_size, void* d_ws, size_t ws_size,
                              hipStream_t stream) {
    const float* Fm = (const float*)d_in[0];
    const float* W  = (const float*)d_in[1];
    const int* idx  = (const int*)d_in[2];
    const int* mol  = (const int*)d_in[3];
    float* out = (float*)d_out;

    const int N = in_sizes[0] / FDIM;   // 50000
    const int E = in_sizes[3];          // 1600000

    const int nb = (N + BROWS - 1) / BROWS;   // 1563 buckets

    // workspace layout (~27 MB)
    char* ws = (char*)d_ws;
    size_t o = 0;
    unsigned short* WsH = (unsigned short*)(ws + o); o += 32 * 1024;
    unsigned short* WsL = (unsigned short*)(ws + o); o += 32 * 1024;
    unsigned short* Gh = (unsigned short*)(ws + o);  o += ((size_t)N * FDIM * 2 + 255) & ~(size_t)255;
    unsigned* sortedE = (unsigned*)(ws + o);         o += ((size_t)E * 4 + 255) & ~(size_t)255;
    unsigned* M = (unsigned*)(ws + o);               o += ((size_t)NBLK * nb * 4 + 255) & ~(size_t)255;
    unsigned* tot = (unsigned*)(ws + o);             o += ((size_t)nb * 4 + 255) & ~(size_t)255;
    unsigned* bucketStart = (unsigned*)(ws + o);     o += ((size_t)(nb + 1) * 4 + 255) & ~(size_t)255;
    float* part = (float*)(ws + o);                  o += (size_t)nb * 1024 * sizeof(float);
    float* partial = (float*)(ws + o);               o += NSLICE * 1024 * sizeof(float);

    make_ws2<<<64, 256, 0, stream>>>(W, WsH, WsL);
    gemm_mfma<<<(N + 127) / 128, 512, 0, stream>>>(Fm, WsH, WsL, Gh, N);

    size_t smem = (size_t)nb * 4;
    k_hist<<<NBLK, 1024, smem, stream>>>(idx, E, nb, M);
    k_mscan2<<<(nb + 3) / 4, 256, 0, stream>>>(M, nb, tot);
    k_bscan<<<1, 256, 0, stream>>>(tot, nb, bucketStart);
    k_scatter<<<NBLK, 1024, smem, stream>>>(idx, mol, E, nb, M, bucketStart, sortedE);

    edge_kernel<<<nb, 512, 0, stream>>>(Gh, Fm, sortedE, bucketStart, part, N, out_size);

    k_red1<<<NSLICE * 4, 256, 0, stream>>>(part, nb, partial, out_size);
    k_red2<<<(out_size + 255) / 256, 256, 0, stream>>>(partial, out, out_size);
}